// Round 4
// baseline (410.903 us; speedup 1.0000x reference)
//
#include <hip/hip_runtime.h>
#include <stdint.h>

#define N_ROWS 16384
#define DIM    512

typedef __bf16 v8bf __attribute__((ext_vector_type(8)));
typedef float  v4f  __attribute__((ext_vector_type(4)));
typedef unsigned long long u64;

union I4B8 { int4 i; v8bf b; };
__device__ __forceinline__ v8bf as_v8bf(int4 v) { I4B8 u; u.i = v; return u.b; }

// Round-to-nearest-even fp32 -> bf16
__device__ __forceinline__ ushort bf16_rne(float f) {
    unsigned u = __float_as_uint(f);
    unsigned r = u + 0x7FFFu + ((u >> 16) & 1u);
    return (ushort)(r >> 16);
}

// Monotonic float -> sortable u32 key
__device__ __forceinline__ unsigned fkey(float f) {
    unsigned u = __float_as_uint(f);
    return (u & 0x80000000u) ? ~u : (u | 0x80000000u);
}

// Async global->LDS, 16B per lane. LDS dest = wave-uniform base + lane*16.
__device__ __forceinline__ void gload_lds16(const void* g, void* l) {
    __builtin_amdgcn_global_load_lds(
        (const __attribute__((address_space(1))) unsigned int*)g,
        (__attribute__((address_space(3))) unsigned int*)l,
        16, 0, 0);
}

// ---------------- kernel 1: fp32 -> bf16 convert (+ table zero-init) ----------------
__global__ __launch_bounds__(256)
void convert_bf16_kernel(const float* __restrict__ x, ushort* __restrict__ xb,
                         u64* __restrict__ table) {
    int tid    = blockIdx.x * blockDim.x + threadIdx.x;
    int stride = gridDim.x * blockDim.x;
    if (tid < N_ROWS) table[tid] = 0;          // replaces a separate memset dispatch
    const float4* x4  = (const float4*)x;
    ushort4*      xb4 = (ushort4*)xb;
    const int n4 = (N_ROWS * DIM) / 4;
    for (int i = tid; i < n4; i += stride) {
        float4 v = x4[i];
        ushort4 o;
        o.x = bf16_rne(v.x);
        o.y = bf16_rne(v.y);
        o.z = bf16_rne(v.z);
        o.w = bf16_rne(v.w);
        xb4[i] = o;
    }
}

// ---------------- kernel 2: symmetric tiled GEMM + fused argmax ----------------
// Triangle-fold schedule (r3): b = u*64 + p; u<=p -> (127-p,127-u), else (p,u-1).
// NEW in r4: cross-round double-buffered LDS staging. Round k's loads are issued
// one round early; the pre-compute wait is s_waitcnt vmcnt(8) (oldest 8 = this
// round's buffer) via inline asm, so prefetch latency hides under round k-1's
// MFMAs instead of draining at a vmcnt(0) barrier (the m97 structural stall).
// LDS chunk layout unchanged: L in [0,1024): row=(L>>9)*64+((L>>6)&3)*16+(L&15),
// kchunk=((L>>8)&1)*4+((L>>4)&3) -> every frag ds_read_b128 = base+lane*16.
__global__ __launch_bounds__(256)
void argmax_dots_kernel(const ushort* __restrict__ xb, u64* __restrict__ table) {
    __shared__ __attribute__((aligned(16))) ushort ldsA[2][128 * 64];  // 2 x 16 KB
    __shared__ __attribute__((aligned(16))) ushort ldsB[2][128 * 64];  // 2 x 16 KB

    const int u = blockIdx.x >> 6;
    const int p = blockIdx.x & 63;
    const int rT = (u <= p) ? (127 - p) : p;
    const int cT = (u <= p) ? (127 - u) : (u - 1);

    const int t      = threadIdx.x;
    const int lane   = t & 63;
    const int wave   = t >> 6;
    const int lane15 = lane & 15;
    const int quad   = lane >> 4;
    const int rh = wave >> 1;
    const int ch = wave & 1;

    const int rowBase = rT * 128;
    const int colBase = cT * 128;

    const ushort* gA[4];
    const ushort* gB[4];
#pragma unroll
    for (int j = 0; j < 4; ++j) {
        const int L = j * 256 + t;
        const int srow = ((L >> 9) << 6) + (((L >> 6) & 3) << 4) + (L & 15);
        const int skc  = (((L >> 8) & 1) << 2) + ((L >> 4) & 3);
        gA[j] = xb + (size_t)(rowBase + srow) * DIM + skc * 8;
        gB[j] = xb + (size_t)(colBase + srow) * DIM + skc * 8;
    }
    const int dstOff = wave * 1024;

    v4f acc[4][4];
#pragma unroll
    for (int rf = 0; rf < 4; ++rf)
#pragma unroll
        for (int cf = 0; cf < 4; ++cf) {
            v4f z = {0.f, 0.f, 0.f, 0.f};
            acc[rf][cf] = z;
        }

    // prefetch round 0 into buffer 0 (8 issues: 4 A + 4 B)
#pragma unroll
    for (int j = 0; j < 4; ++j) {
        gload_lds16(gA[j], (char*)ldsA[0] + j * 4096 + dstOff);
        gload_lds16(gB[j], (char*)ldsB[0] + j * 4096 + dstOff);
    }

#pragma unroll
    for (int k = 0; k < 8; ++k) {           // 8 K-rounds, fully unrolled
        const int cur = k & 1;
        if (k < 7) {                        // prefetch round k+1 into other buffer
            const int kk = (k + 1) * 64;
            const int nb = cur ^ 1;
#pragma unroll
            for (int j = 0; j < 4; ++j) {
                gload_lds16(gA[j] + kk, (char*)ldsA[nb] + j * 4096 + dstOff);
                gload_lds16(gB[j] + kk, (char*)ldsB[nb] + j * 4096 + dstOff);
            }
            // wait only this round's 8 loads (oldest); prefetch stays in flight
            asm volatile("s_waitcnt vmcnt(8)\n\ts_barrier" ::: "memory");
        } else {
            asm volatile("s_waitcnt vmcnt(0)\n\ts_barrier" ::: "memory");
        }

#pragma unroll
        for (int s = 0; s < 2; ++s) {
            int4 ar[4], br[4];
#pragma unroll
            for (int rf = 0; rf < 4; ++rf)
                ar[rf] = *(const int4*)((const char*)ldsA[cur] + rh * 8192 + s * 4096 + rf * 1024 + lane * 16);
#pragma unroll
            for (int cf = 0; cf < 4; ++cf)
                br[cf] = *(const int4*)((const char*)ldsB[cur] + ch * 8192 + s * 4096 + cf * 1024 + lane * 16);
#pragma unroll
            for (int rf = 0; rf < 4; ++rf)
#pragma unroll
                for (int cf = 0; cf < 4; ++cf)
                    acc[rf][cf] = __builtin_amdgcn_mfma_f32_16x16x32_bf16(
                        as_v8bf(ar[rf]), as_v8bf(br[cf]), acc[rf][cf], 0, 0, 0);
        }
        // all waves done reading buf[cur] before next round's prefetch overwrites it
        asm volatile("s_barrier" ::: "memory");
    }

    // ---- epilogue: row-side argmax (C/D layout: col=lane15+16*cf, row=quad*4+e) ----
    const int colLane = colBase + ch * 64 + lane15;
#pragma unroll
    for (int rf = 0; rf < 4; ++rf) {
#pragma unroll
        for (int e = 0; e < 4; ++e) {
            const int row = rowBase + rh * 64 + rf * 16 + quad * 4 + e;
            float bv = -3.0e38f;
            int   bc = 0;
#pragma unroll
            for (int cf = 0; cf < 4; ++cf) {
                const float v = acc[rf][cf][e];
                const int col = colLane + cf * 16;
                if (v > bv && col != row) { bv = v; bc = col; }
            }
            u64 packed = ((u64)fkey(bv) << 32) | (unsigned)(~bc);
#pragma unroll
            for (int m = 1; m < 16; m <<= 1) {
                u64 o = __shfl_xor(packed, m, 64);
                if (o > packed) packed = o;
            }
            if (lane15 == 0) atomicMax(&table[row], packed);
        }
    }

    // ---- epilogue: col-side (transposed) argmax for off-diagonal tiles ----
    if (rT != cT) {
#pragma unroll
        for (int cf = 0; cf < 4; ++cf) {
            const int col = colLane + cf * 16;
            float bv = -3.0e38f;
            int   br_ = 0;
#pragma unroll
            for (int rf = 0; rf < 4; ++rf)
#pragma unroll
                for (int e = 0; e < 4; ++e) {
                    const float v = acc[rf][cf][e];
                    const int row = rowBase + rh * 64 + rf * 16 + quad * 4 + e;
                    if (v > bv) { bv = v; br_ = row; }
                }
            u64 packed = ((u64)fkey(bv) << 32) | (unsigned)(~br_);
            u64 o = __shfl_xor(packed, 16, 64); if (o > packed) packed = o;
            o     = __shfl_xor(packed, 32, 64); if (o > packed) packed = o;
            if (quad == 0) atomicMax(&table[col], packed);
        }
    }
}

// ---------------- kernel 3: rho + loss epilogue (fp32 exact) ----------------
__global__ __launch_bounds__(256)
void rho_loss_kernel(const float* __restrict__ x, const u64* __restrict__ table,
                     float* __restrict__ out) {
    const int lane = threadIdx.x & 63;
    const int wave = threadIdx.x >> 6;
    const int waveGlobal = blockIdx.x * 4 + wave;   // 2048 waves

    float local = 0.f;
    for (int r8 = 0; r8 < 8; ++r8) {
        const int row = waveGlobal * 8 + r8;
        const u64 packed = table[row];
        const int nb = (int)(~(unsigned)(packed & 0xFFFFFFFFu));

        const float4* xr = (const float4*)(x + (size_t)row * DIM);
        const float4* xn = (const float4*)(x + (size_t)nb  * DIM);
        float s = 0.f;
#pragma unroll
        for (int tt = 0; tt < 2; ++tt) {
            float4 a = xr[lane * 2 + tt];
            float4 b = xn[lane * 2 + tt];
            float d0 = a.x - b.x + 1e-6f;
            float d1 = a.y - b.y + 1e-6f;
            float d2 = a.z - b.z + 1e-6f;
            float d3 = a.w - b.w + 1e-6f;
            s += d0 * d0 + d1 * d1 + d2 * d2 + d3 * d3;
        }
#pragma unroll
        for (int m = 1; m < 64; m <<= 1) s += __shfl_xor(s, m, 64);

        if (lane == 0) {
            float rho = sqrtf(s);
            local += logf(rho + 1e-8f);
        }
    }
    if (lane == 0) atomicAdd(out, -local * (1.0f / 16384.0f));
}

extern "C" void kernel_launch(void* const* d_in, const int* in_sizes, int n_in,
                              void* d_out, int out_size, void* d_ws, size_t ws_size,
                              hipStream_t stream) {
    const float* x = (const float*)d_in[0];

    // Workspace: [0, 16 MiB) bf16 x; then 16384 x u64 argmax table.
    ushort* xb    = (ushort*)d_ws;
    u64*    table = (u64*)((char*)d_ws + (size_t)N_ROWS * DIM * sizeof(ushort));
    float*  out   = (float*)d_out;

    hipMemsetAsync(out, 0, sizeof(float), stream);

    convert_bf16_kernel<<<2048, 256, 0, stream>>>(x, xb, table);
    argmax_dots_kernel<<<8256, 256, 0, stream>>>(xb, table);
    rho_loss_kernel<<<512, 256, 0, stream>>>(x, table, out);
}